// Round 6
// baseline (1742.387 us; speedup 1.0000x reference)
//
#include <hip/hip_runtime.h>

// ---------------------------------------------------------------------------
// Problem constants
// ---------------------------------------------------------------------------
constexpr int NN = 50000;            // nodes
constexpr int NE = 800000;           // edges (before self loops)
constexpr int NP = 262144;           // pairs
constexpr int ET = NE + NN;          // edges incl self loops

using short8 = __attribute__((ext_vector_type(8))) short;
using f32x4  = __attribute__((ext_vector_type(4))) float;

__device__ __forceinline__ ushort f2b(float f) {   // fp32 -> bf16 RNE
  unsigned u = __float_as_uint(f);
  return (ushort)((u + 0x7FFFu + ((u >> 16) & 1u)) >> 16);
}
__device__ __forceinline__ float b2f(ushort b) {
  return __uint_as_float(((unsigned)b) << 16);
}
__device__ __forceinline__ float lrelu(float a) { return a > 0.f ? a : 0.2f * a; }

// ---------------------------------------------------------------------------
// bf16 MFMA GEMM: C[M,N] = A[M,Kpad] @ BT[Npad,Kpad]^T  (+bias)
// 128x128 block tile, BK=32, 4 waves of 64x64 (4x4 grid of 16x16x32 MFMA).
// STATS: per-column sum/sumsq of (pre-rounding) output -> stats (N==128 only).
// ---------------------------------------------------------------------------
template<bool OUT_BF16, bool STATS>
__global__ __launch_bounds__(256)
void mfma_gemm(const ushort* __restrict__ A, const ushort* __restrict__ BT,
               void* __restrict__ Cp, int M, int N, int Kpad, int Cld,
               const float* __restrict__ bias,
               double* __restrict__ stats)
{
  __shared__ __align__(16) ushort As[128 * 40];  // +8 pad: 2-way bank alias max
  __shared__ __align__(16) ushort Bs[128 * 40];
  const int tid = threadIdx.x;
  const int lane = tid & 63;
  const int wave = tid >> 6;
  const int row0 = blockIdx.y * 128, col0 = blockIdx.x * 128;
  const int wm = (wave >> 1) * 64, wn = (wave & 1) * 64;
  const int lrow = lane & 15, lk = (lane >> 4) * 8;

  f32x4 acc[4][4];
  #pragma unroll
  for (int i = 0; i < 4; ++i)
    #pragma unroll
    for (int j = 0; j < 4; ++j)
      acc[i][j] = (f32x4){0.f, 0.f, 0.f, 0.f};

  for (int kt = 0; kt < Kpad; kt += 32) {
    #pragma unroll
    for (int c = tid; c < 512; c += 256) {
      int m = c >> 2, c8 = c & 3;
      int r = row0 + m;
      int kk = kt + c8 * 8;
      uint4 v = {0u, 0u, 0u, 0u};
      if (r < M) v = *(const uint4*)(A + (size_t)r * Kpad + kk);
      *(uint4*)(As + m * 40 + c8 * 8) = v;
    }
    #pragma unroll
    for (int c = tid; c < 512; c += 256) {
      int n = c >> 2, c8 = c & 3;
      *(uint4*)(Bs + n * 40 + c8 * 8) =
          *(const uint4*)(BT + (size_t)(col0 + n) * Kpad + kt + c8 * 8);
    }
    __syncthreads();

    short8 af[4], bfr[4];
    #pragma unroll
    for (int i = 0; i < 4; ++i)
      af[i] = *(const short8*)(As + (wm + i * 16 + lrow) * 40 + lk);
    #pragma unroll
    for (int j = 0; j < 4; ++j)
      bfr[j] = *(const short8*)(Bs + (wn + j * 16 + lrow) * 40 + lk);
    #pragma unroll
    for (int i = 0; i < 4; ++i)
      #pragma unroll
      for (int j = 0; j < 4; ++j)
        acc[i][j] = __builtin_amdgcn_mfma_f32_16x16x32_bf16(af[i], bfr[j],
                                                            acc[i][j], 0, 0, 0);
    __syncthreads();
  }

  // epilogue: D mapping col=lane&15, row=(lane>>4)*4+reg
  float* sacc = (float*)As;                 // reuse LDS: [128]{sum,sumsq}
  if constexpr (STATS) {
    sacc[tid] = 0.f;
    __syncthreads();
  }
  float cs[4] = {0.f, 0.f, 0.f, 0.f}, cq[4] = {0.f, 0.f, 0.f, 0.f};
  #pragma unroll
  for (int i = 0; i < 4; ++i) {
    int r0 = row0 + wm + i * 16 + (lane >> 4) * 4;
    #pragma unroll
    for (int j = 0; j < 4; ++j) {
      int col = col0 + wn + j * 16 + lrow;
      if (col >= N) continue;
      float bv = bias ? bias[col] : 0.f;
      #pragma unroll
      for (int rg = 0; rg < 4; ++rg) {
        int row = r0 + rg;
        if (row >= M) continue;
        float val = acc[i][j][rg] + bv;
        if (OUT_BF16)
          ((ushort*)Cp)[(size_t)row * Cld + col] = f2b(val);
        else
          ((float*)Cp)[(size_t)row * Cld + col] = val;
        if (STATS) { cs[j] += val; cq[j] += val * val; }
      }
    }
  }
  if constexpr (STATS) {
    #pragma unroll
    for (int j = 0; j < 4; ++j) {
      int cl = wn + j * 16 + lrow;          // local col (N==128, col0==0)
      atomicAdd(&sacc[2 * cl + 0], cs[j]);
      atomicAdd(&sacc[2 * cl + 1], cq[j]);
    }
    __syncthreads();
    if (tid < 128) {
      unsafeAtomicAdd(&stats[tid],       (double)sacc[2 * tid + 0]);
      unsafeAtomicAdd(&stats[128 + tid], (double)sacc[2 * tid + 1]);
    }
  }
}

// ---------------------------------------------------------------------------
// Weight prep, one kernel (all bf16 BT[Npad][Kpad], zero-padded):
//   [0,294912)        W1T  [512][576] <- W1  (572x512)
//   [294912,425984)   W2T  [512][256] <- W2  (256x512)
//   [425984,491520)   PWT  [256][256] <- lw1 split: out n<128 top half rows,
//                                        n>=128 bottom half rows
//   [491520,507904)   LW2T [128][128] <- lw2 (128x128)
//   [507904,524288)   FWT  [128][128] <- fw  (128x65)
//   [524288,524544)   biasP[256] fp32: lb1 for c<128 else 0
// ---------------------------------------------------------------------------
__global__ void prep_weights(const float* __restrict__ W1, ushort* __restrict__ W1T,
                             const float* __restrict__ W2, ushort* __restrict__ W2T,
                             const float* __restrict__ lw1, ushort* __restrict__ PWT,
                             const float* __restrict__ lw2, ushort* __restrict__ LW2T,
                             const float* __restrict__ fw, ushort* __restrict__ FWT,
                             const float* __restrict__ lb1, float* __restrict__ biasP)
{
  int i = blockIdx.x * blockDim.x + threadIdx.x;
  if (i >= 524544) return;
  if (i >= 524288) {
    int c = i - 524288;
    biasP[c] = (c < 128) ? lb1[c] : 0.f;
    return;
  }
  if (i < 294912) {
    int n = i / 576, k = i % 576;
    W1T[i] = f2b((k < 572) ? W1[(size_t)k * 512 + n] : 0.f);
  } else if (i < 425984) {
    int j = i - 294912; int n = j / 256, k = j % 256;
    W2T[j] = f2b(W2[(size_t)k * 512 + n]);
  } else if (i < 491520) {
    int j = i - 425984; int n = j / 256, k = j % 256;
    float v = (n < 128) ? lw1[(size_t)k * 128 + n]
                        : lw1[(size_t)(k + 256) * 128 + (n - 128)];
    PWT[j] = f2b(v);
  } else if (i < 507904) {
    int j = i - 491520; int n = j / 128, k = j % 128;
    LW2T[j] = f2b(lw2[(size_t)k * 128 + n]);
  } else {
    int j = i - 507904; int n = j / 128, k = j % 128;
    FWT[j] = f2b((n < 65) ? fw[(size_t)k * 65 + n] : 0.f);
  }
}

// x[NN][572] fp32 -> xb[NN][576] bf16 (zero padded), 4 cols/thread
__global__ void conv_x(const float* __restrict__ x, ushort* __restrict__ xb)
{
  int i = blockIdx.x * blockDim.x + threadIdx.x;
  if (i >= NN * 144) return;
  int r = i / 144, c4 = (i % 144) * 4;
  ushort4 o = {0, 0, 0, 0};
  if (c4 < 572) {
    float4 v = *(const float4*)(x + (size_t)r * 572 + c4);
    o.x = f2b(v.x); o.y = f2b(v.y); o.z = f2b(v.z); o.w = f2b(v.w);
  }
  *(ushort4*)(xb + (size_t)r * 576 + c4) = o;
}

// ---------------------------------------------------------------------------
// CSR build + degree-descending permutation
// ---------------------------------------------------------------------------
__global__ void deg_count(const int* __restrict__ ei, int* __restrict__ deg)
{
  int e = blockIdx.x * blockDim.x + threadIdx.x;
  if (e >= ET) return;
  int dst = (e < NE) ? ei[NE + e] : e - NE;
  atomicAdd(&deg[dst], 1);
}

__global__ __launch_bounds__(1024)
void scan_deg(const int* __restrict__ deg, int* __restrict__ rowptr,
              int* __restrict__ cursor)
{
  __shared__ int tot[1024];
  const int t = threadIdx.x;
  const int CH = (NN + 1023) / 1024;
  const int base = t * CH;
  int s = 0;
  for (int i = 0; i < CH; ++i) {
    int idx = base + i;
    if (idx < NN) s += deg[idx];
  }
  tot[t] = s;
  __syncthreads();
  for (int off = 1; off < 1024; off <<= 1) {
    int v = (t >= off) ? tot[t - off] : 0;
    __syncthreads();
    tot[t] += v;
    __syncthreads();
  }
  int run = (t == 0) ? 0 : tot[t - 1];
  for (int i = 0; i < CH; ++i) {
    int idx = base + i;
    if (idx <= NN) { rowptr[idx] = run; if (idx < NN) cursor[idx] = run; }
    if (idx < NN) run += deg[idx];
  }
}

__global__ void scatter_edges(const int* __restrict__ ei, int* __restrict__ cursor,
                              int* __restrict__ csr_src)
{
  int e = blockIdx.x * blockDim.x + threadIdx.x;
  if (e >= ET) return;
  int src, dst;
  if (e < NE) { src = ei[e]; dst = ei[NE + e]; }
  else        { src = dst = e - NE; }
  int pos = atomicAdd(&cursor[dst], 1);
  csr_src[pos] = src;
}

__global__ void deg_hist(const int* __restrict__ deg, int* __restrict__ hist)
{
  int n = blockIdx.x * blockDim.x + threadIdx.x;
  if (n >= NN) return;
  int d = deg[n]; if (d > 255) d = 255;
  atomicAdd(&hist[255 - d], 1);
}

__global__ void scan_hist(const int* __restrict__ hist, int* __restrict__ hcur)
{
  __shared__ int sh[256];
  int t = threadIdx.x;
  int v0 = hist[t];
  sh[t] = v0;
  __syncthreads();
  for (int off = 1; off < 256; off <<= 1) {
    int v = (t >= off) ? sh[t - off] : 0;
    __syncthreads();
    sh[t] += v;
    __syncthreads();
  }
  hcur[t] = sh[t] - v0;                // exclusive
}

__global__ void build_perm(const int* __restrict__ deg, int* __restrict__ hcur,
                           int* __restrict__ perm)
{
  int n = blockIdx.x * blockDim.x + threadIdx.x;
  if (n >= NN) return;
  int d = deg[n]; if (d > 255) d = 255;
  int pos = atomicAdd(&hcur[255 - d], 1);
  perm[pos] = n;
}

// ---------------------------------------------------------------------------
// GAT helpers (h in bf16)
// ---------------------------------------------------------------------------
__global__ void node_coeffs(const ushort* __restrict__ hb,
                            const float* __restrict__ a_src,
                            const float* __restrict__ a_dst,
                            float* __restrict__ s_n, float* __restrict__ d_n)
{
  int node = (blockIdx.x * blockDim.x + threadIdx.x) >> 6;
  int lane = threadIdx.x & 63;
  if (node >= NN) return;
  int head = lane >> 5;
  int cidx = (lane * 8) & 255;
  short8 hv = *(const short8*)(hb + (size_t)node * 512 + lane * 8);
  float4 a0 = *(const float4*)(a_src + head * 256 + cidx);
  float4 a1 = *(const float4*)(a_src + head * 256 + cidx + 4);
  float4 d0 = *(const float4*)(a_dst + head * 256 + cidx);
  float4 d1 = *(const float4*)(a_dst + head * 256 + cidx + 4);
  float h0 = b2f((ushort)hv[0]), h1 = b2f((ushort)hv[1]);
  float h2 = b2f((ushort)hv[2]), h3 = b2f((ushort)hv[3]);
  float h4 = b2f((ushort)hv[4]), h5 = b2f((ushort)hv[5]);
  float h6 = b2f((ushort)hv[6]), h7 = b2f((ushort)hv[7]);
  float ss = h0*a0.x + h1*a0.y + h2*a0.z + h3*a0.w
           + h4*a1.x + h5*a1.y + h6*a1.z + h7*a1.w;
  float dd = h0*d0.x + h1*d0.y + h2*d0.z + h3*d0.w
           + h4*d1.x + h5*d1.y + h6*d1.z + h7*d1.w;
  #pragma unroll
  for (int off = 16; off > 0; off >>= 1) {
    ss += __shfl_xor(ss, off);
    dd += __shfl_xor(dd, off);
  }
  if ((lane & 31) == 0) {
    s_n[node * 2 + head] = ss;
    d_n[node * 2 + head] = dd;
  }
}

// One wave handles 4 dst nodes (degree-sorted). Lanes 0-31: head0, 32-63:
// head1; one 16-B ushort8 row-load per lane per edge. Softmax exp-values
// cached in lane registers (deg<=64 fast path) and broadcast via shfl.
// Output bf16 + fused BN partial stats.
__global__ __launch_bounds__(256)
void gat_aggregate(const int* __restrict__ perm,
                   const int* __restrict__ rowptr, const int* __restrict__ csr_src,
                   const ushort* __restrict__ hb,
                   const float* __restrict__ s_n, const float* __restrict__ d_n,
                   const float* __restrict__ bias, ushort* __restrict__ outp,
                   double* __restrict__ stats)
{
  __shared__ float sacc[512];               // [256] sum, [256] sumsq
  sacc[threadIdx.x] = 0.f;
  sacc[256 + threadIdx.x] = 0.f;
  __syncthreads();

  const int wave = threadIdx.x >> 6, lane = threadIdx.x & 63;
  const int base = blockIdx.x * 16 + wave * 4;
  const bool hi = lane >= 32;
  const int ch0 = (lane & 31) * 8;
  const float4 bba = *(const float4*)(bias + ch0);
  const float4 bbb = *(const float4*)(bias + ch0 + 4);
  const float bias8[8] = {bba.x, bba.y, bba.z, bba.w, bbb.x, bbb.y, bbb.z, bbb.w};
  const float2* sn2 = (const float2*)s_n;

  float ssum[8] = {0,0,0,0,0,0,0,0}, ssq[8] = {0,0,0,0,0,0,0,0};

  for (int n = 0; n < 4; ++n) {
    const int idx = base + n;
    if (idx >= NN) continue;
    const int dst = perm[idx];
    const int beg = rowptr[dst], end = rowptr[dst + 1];
    const int cnt = end - beg;
    const float d0 = d_n[dst * 2 + 0], d1 = d_n[dst * 2 + 1];

    float acc[8] = {0,0,0,0,0,0,0,0};

    if (cnt <= 64) {
      // --- fast path: one edge per lane ---
      float a0 = -1e30f, a1 = -1e30f;
      if (lane < cnt) {
        float2 sv = sn2[csr_src[beg + lane]];
        a0 = lrelu(sv.x + d0);
        a1 = lrelu(sv.y + d1);
      }
      float m0 = a0, m1 = a1;
      #pragma unroll
      for (int off = 32; off > 0; off >>= 1) {
        m0 = fmaxf(m0, __shfl_xor(m0, off));
        m1 = fmaxf(m1, __shfl_xor(m1, off));
      }
      float ez0 = (lane < cnt) ? __expf(a0 - m0) : 0.f;
      float ez1 = (lane < cnt) ? __expf(a1 - m1) : 0.f;
      float z0 = ez0, z1 = ez1;
      #pragma unroll
      for (int off = 32; off > 0; off >>= 1) {
        z0 += __shfl_xor(z0, off);
        z1 += __shfl_xor(z1, off);
      }
      const float rz0 = 1.f / (z0 + 1e-16f);
      const float rz1 = 1.f / (z1 + 1e-16f);

      int li = 0;
      for (; li + 2 <= cnt; li += 2) {
        int sA = csr_src[beg + li], sB = csr_src[beg + li + 1];
        short8 hA = *(const short8*)(hb + (size_t)sA * 512 + lane * 8);
        short8 hB = *(const short8*)(hb + (size_t)sB * 512 + lane * 8);
        float wA0 = __shfl(ez0, li) * rz0,     wA1 = __shfl(ez1, li) * rz1;
        float wB0 = __shfl(ez0, li + 1) * rz0, wB1 = __shfl(ez1, li + 1) * rz1;
        float wA = hi ? wA1 : wA0;
        float wB = hi ? wB1 : wB0;
        #pragma unroll
        for (int k = 0; k < 8; ++k) {
          acc[k] = fmaf(b2f((ushort)hA[k]), wA, acc[k]);
          acc[k] = fmaf(b2f((ushort)hB[k]), wB, acc[k]);
        }
      }
      if (li < cnt) {
        int sA = csr_src[beg + li];
        short8 hA = *(const short8*)(hb + (size_t)sA * 512 + lane * 8);
        float wA0 = __shfl(ez0, li) * rz0, wA1 = __shfl(ez1, li) * rz1;
        float wA = hi ? wA1 : wA0;
        #pragma unroll
        for (int k = 0; k < 8; ++k)
          acc[k] = fmaf(b2f((ushort)hA[k]), wA, acc[k]);
      }
    } else {
      // --- general path (deg > 64, rare) ---
      float m0 = -1e30f, m1 = -1e30f;
      for (int i = beg + lane; i < end; i += 64) {
        float2 sv = sn2[csr_src[i]];
        m0 = fmaxf(m0, lrelu(sv.x + d0));
        m1 = fmaxf(m1, lrelu(sv.y + d1));
      }
      #pragma unroll
      for (int off = 32; off > 0; off >>= 1) {
        m0 = fmaxf(m0, __shfl_xor(m0, off));
        m1 = fmaxf(m1, __shfl_xor(m1, off));
      }
      float z0 = 0.f, z1 = 0.f;
      for (int i = beg + lane; i < end; i += 64) {
        float2 sv = sn2[csr_src[i]];
        z0 += __expf(lrelu(sv.x + d0) - m0);
        z1 += __expf(lrelu(sv.y + d1) - m1);
      }
      #pragma unroll
      for (int off = 32; off > 0; off >>= 1) {
        z0 += __shfl_xor(z0, off);
        z1 += __shfl_xor(z1, off);
      }
      const float rz0 = 1.f / (z0 + 1e-16f);
      const float rz1 = 1.f / (z1 + 1e-16f);
      for (int i = beg; i < end; ++i) {
        int s = csr_src[i];
        float2 sv = sn2[s];
        float w0 = __expf(lrelu(sv.x + d0) - m0) * rz0;
        float w1 = __expf(lrelu(sv.y + d1) - m1) * rz1;
        float w = hi ? w1 : w0;
        short8 hv = *(const short8*)(hb + (size_t)s * 512 + lane * 8);
        #pragma unroll
        for (int k = 0; k < 8; ++k)
          acc[k] = fmaf(b2f((ushort)hv[k]), w, acc[k]);
      }
    }

    // head mean (xor-32 combine) + bias, bf16 store, stats accumulate
    float ov[8];
    #pragma unroll
    for (int k = 0; k < 8; ++k)
      ov[k] = 0.5f * (acc[k] + __shfl_xor(acc[k], 32)) + bias8[k];

    ushort* op = outp + (size_t)dst * 256 + ch0;
    if (!hi) {
      ushort4 o = {f2b(ov[0]), f2b(ov[1]), f2b(ov[2]), f2b(ov[3])};
      *(ushort4*)op = o;
      #pragma unroll
      for (int k = 0; k < 8; ++k) { ssum[k] += ov[k]; ssq[k] += ov[k] * ov[k]; }
    } else {
      ushort4 o = {f2b(ov[4]), f2b(ov[5]), f2b(ov[6]), f2b(ov[7])};
      *(ushort4*)(op + 4) = o;
    }
  }

  if (!hi) {
    #pragma unroll
    for (int k = 0; k < 8; ++k) {
      atomicAdd(&sacc[ch0 + k], ssum[k]);
      atomicAdd(&sacc[256 + ch0 + k], ssq[k]);
    }
  }
  __syncthreads();
  const int c = threadIdx.x;
  unsafeAtomicAdd(&stats[c],       (double)sacc[c]);
  unsafeAtomicAdd(&stats[256 + c], (double)sacc[256 + c]);
}

// ---------------------------------------------------------------------------
// Pair build: z1[p,c] = P[i0[p], c] + P[i1[p], 128+c]  (bias pre-folded into
// P's first half). bf16 out + fused BN stats. Grid 2048 blocks x 128 pairs.
// ---------------------------------------------------------------------------
__global__ __launch_bounds__(256)
void pair_add(const ushort* __restrict__ P, const int* __restrict__ id0,
              const int* __restrict__ id1, ushort* __restrict__ z1b,
              double* __restrict__ stats)
{
  __shared__ float sacc[256];               // [128] sum, [128] sumsq
  sacc[threadIdx.x] = 0.f;
  __syncthreads();
  const int wave = threadIdx.x >> 6, lane = threadIdx.x & 63;
  const int c = lane * 2;
  const int pbase = blockIdx.x * 128 + wave * 32;
  float s0 = 0.f, s1 = 0.f, q0 = 0.f, q1 = 0.f;
  for (int k = 0; k < 32; ++k) {
    int p = pbase + k;
    int a = id0[p], b = id1[p];
    ushort2 ua = *(const ushort2*)(P + (size_t)a * 256 + c);
    ushort2 ub = *(const ushort2*)(P + (size_t)b * 256 + 128 + c);
    float zx = b2f(ua.x) + b2f(ub.x);
    float zy = b2f(ua.y) + b2f(ub.y);
    ushort2 o = {f2b(zx), f2b(zy)};
    *(ushort2*)(z1b + (size_t)p * 128 + c) = o;
    s0 += zx; s1 += zy; q0 += zx * zx; q1 += zy * zy;
  }
  atomicAdd(&sacc[c], s0);       atomicAdd(&sacc[c + 1], s1);
  atomicAdd(&sacc[128 + c], q0); atomicAdd(&sacc[128 + c + 1], q1);
  __syncthreads();
  unsafeAtomicAdd(&stats[threadIdx.x], (double)sacc[threadIdx.x]);
}

// ---------------------------------------------------------------------------
// BatchNorm apply (+ReLU), bf16 in -> bf16 out (in-place safe)
// ---------------------------------------------------------------------------
__global__ void bn_apply_b(const ushort* __restrict__ xin, ushort* __restrict__ y,
                           const double* __restrict__ stats,
                           const float* __restrict__ g, const float* __restrict__ b,
                           int total4, int cols, float inv_rows)
{
  int i = blockIdx.x * blockDim.x + threadIdx.x;
  if (i >= total4) return;
  int base = i * 4;
  int c = base % cols;
  ushort4 xv = *(const ushort4*)(xin + base);
  float4 gv = *(const float4*)(g + c);
  float4 bv = *(const float4*)(b + c);
  ushort4 o;
  #pragma unroll
  for (int k = 0; k < 4; ++k) {
    float mean = (float)(stats[c + k] * (double)inv_rows);
    float var = (float)(stats[cols + c + k] * (double)inv_rows) - mean * mean;
    float sc = ((const float*)&gv)[k] * rsqrtf(var + 1e-5f);
    float sh = ((const float*)&bv)[k] - mean * sc;
    float v = fmaxf(fmaf(b2f(((const ushort*)&xv)[k]), sc, sh), 0.f);
    ((ushort*)&o)[k] = f2b(v);
  }
  *(ushort4*)(y + base) = o;
}

// ---------------------------------------------------------------------------
// Host-side GAT layer
// ---------------------------------------------------------------------------
static void gat_layer(const ushort* ain, int Kpad, const ushort* WT,
                      const float* asrc, const float* adst, const float* bias,
                      const float* bng, const float* bnb,
                      const int* perm, const int* rowptr, const int* csr_src,
                      ushort* hb, ushort* tb, ushort* featb,
                      float* s_n, float* d_n, double* stats, hipStream_t st)
{
  dim3 b256(256);
  mfma_gemm<true, false><<<dim3(4, 391), b256, 0, st>>>(
      ain, WT, hb, NN, 512, Kpad, 512, nullptr, nullptr);
  node_coeffs<<<(NN + 3) / 4, b256, 0, st>>>(hb, asrc, adst, s_n, d_n);
  gat_aggregate<<<(NN + 15) / 16, b256, 0, st>>>(perm, rowptr, csr_src, hb,
                                                 s_n, d_n, bias, tb, stats);
  bn_apply_b<<<(NN * 64 + 255) / 256, b256, 0, st>>>(
      tb, featb, stats, bng, bnb, NN * 64, 256, 1.0f / NN);
}

// ---------------------------------------------------------------------------
// kernel_launch
// ---------------------------------------------------------------------------
extern "C" void kernel_launch(void* const* d_in, const int* in_sizes, int n_in,
                              void* d_out, int out_size, void* d_ws, size_t ws_size,
                              hipStream_t stream)
{
  const int*   edge_index = (const int*)d_in[0];
  const float* x      = (const float*)d_in[1];
  const int*   edge_id = (const int*)d_in[2];
  const float* W1     = (const float*)d_in[3];
  const float* a_src1 = (const float*)d_in[4];
  const float* a_dst1 = (const float*)d_in[5];
  const float* b1     = (const float*)d_in[6];
  const float* bn1_g  = (const float*)d_in[7];
  const float* bn1_b  = (const float*)d_in[8];
  const float* W2     = (const float*)d_in[9];
  const float* a_src2 = (const float*)d_in[10];
  const float* a_dst2 = (const float*)d_in[11];
  const float* b2     = (const float*)d_in[12];
  const float* bn2_g  = (const float*)d_in[13];
  const float* bn2_b  = (const float*)d_in[14];
  const float* lw1    = (const float*)d_in[15];
  const float* lb1    = (const float*)d_in[16];
  const float* bn3_g  = (const float*)d_in[17];
  const float* bn3_b  = (const float*)d_in[18];
  const float* lw2    = (const float*)d_in[19];
  const float* lb2    = (const float*)d_in[20];
  const float* bn4_g  = (const float*)d_in[21];
  const float* bn4_b  = (const float*)d_in[22];
  const float* fw     = (const float*)d_in[23];
  const float* fb     = (const float*)d_in[24];
  float* out = (float*)d_out;

  // ---- workspace arena (explicit aliasing) ----
  // Layer phase: xb@0(57.6M) hb@57.6M(51.2M) tb@108.8M(25.6M)
  //              feat1b@160M(25.6M) feat2b@185.6M(25.6M)
  // Pair phase:  z1b@0(67.1M, xb/hb dead) P@70M(25.6M, hb/tb dead)
  //              z2b@100M(67.1M, tb/feat1b dead; feat2b@185.6M safe)
  char* w = (char*)d_ws;
  ushort* xb     = (ushort*)(w + 0);
  ushort* hb     = (ushort*)(w + 57600000);
  ushort* tb     = (ushort*)(w + 108800000);
  ushort* feat1b = (ushort*)(w + 160000000);
  ushort* feat2b = (ushort*)(w + 185600000);
  ushort* z1b    = (ushort*)(w + 0);
  ushort* Pbuf   = (ushort*)(w + 70000000);
  ushort* z2b    = (ushort*)(w + 100000000);
  int*    csr_src = (int*)(w + 294217728);
  int*    deg     = (int*)(w + 297700000);
  int*    rowptr  = (int*)(w + 297900000);
  int*    cursor  = (int*)(w + 298100008);
  float*  s_n     = (float*)(w + 298300008);
  float*  d_n     = (float*)(w + 298700008);
  double* stats   = (double*)(w + 299100008);     // 4 x 512 doubles
  int*    hist    = (int*)(w + 299150000);
  int*    hcur    = (int*)(w + 299151024);
  int*    perm    = (int*)(w + 299160000);        // [NN]
  ushort* W1T     = (ushort*)(w + 300000000);     // [512][576]
  ushort* W2T     = (ushort*)(w + 300600000);     // [512][256]
  ushort* PWT     = (ushort*)(w + 300900000);     // [256][256]
  ushort* LW2T    = (ushort*)(w + 301040000);     // [128][128]
  ushort* FWT     = (ushort*)(w + 301080000);     // [128][128]
  float*  biasP   = (float*)(w + 301200000);      // [256]

  double* st1 = stats,        *st2 = stats + 512;
  double* st3 = stats + 1024, *st4 = stats + 1536;

  dim3 b256(256);

  hipMemsetAsync(stats, 0, 4 * 512 * sizeof(double), stream);
  hipMemsetAsync(hist, 0, 256 * sizeof(int), stream);
  hipMemsetAsync(deg, 0, NN * sizeof(int), stream);

  // ---- weight prep + input convert ----
  prep_weights<<<(524544 + 255) / 256, b256, 0, stream>>>(
      W1, W1T, W2, W2T, lw1, PWT, lw2, LW2T, fw, FWT, lb1, biasP);
  conv_x<<<(NN * 144 + 255) / 256, b256, 0, stream>>>(x, xb);

  // ---- CSR build + degree sort ----
  deg_count<<<(ET + 255) / 256, b256, 0, stream>>>(edge_index, deg);
  scan_deg<<<1, 1024, 0, stream>>>(deg, rowptr, cursor);
  scatter_edges<<<(ET + 255) / 256, b256, 0, stream>>>(edge_index, cursor, csr_src);
  deg_hist<<<(NN + 255) / 256, b256, 0, stream>>>(deg, hist);
  scan_hist<<<1, 256, 0, stream>>>(hist, hcur);
  build_perm<<<(NN + 255) / 256, b256, 0, stream>>>(deg, hcur, perm);

  // ---- GAT layers ----
  gat_layer(xb, 576, W1T, a_src1, a_dst1, b1, bn1_g, bn1_b, perm, rowptr, csr_src,
            hb, tb, feat1b, s_n, d_n, st1, stream);
  gat_layer(feat1b, 256, W2T, a_src2, a_dst2, b2, bn2_g, bn2_b, perm, rowptr, csr_src,
            hb, tb, feat2b, s_n, d_n, st2, stream);

  // ---- pair MLP ----
  // P = feat2 @ [lw1_top | lw1_bot]  (bias lb1 folded into first half)
  mfma_gemm<true, false><<<dim3(2, 391), b256, 0, stream>>>(
      feat2b, PWT, Pbuf, NN, 256, 256, 256, biasP, nullptr);
  pair_add<<<NP / 128, b256, 0, stream>>>(Pbuf, edge_id, edge_id + NP, z1b, st3);
  bn_apply_b<<<(NP * 32 + 255) / 256, b256, 0, stream>>>(
      z1b, z1b, st3, bn3_g, bn3_b, NP * 32, 128, 1.0f / NP);
  mfma_gemm<true, true><<<dim3(1, 2048), b256, 0, stream>>>(
      z1b, LW2T, z2b, NP, 128, 128, 128, lb2, st4);
  bn_apply_b<<<(NP * 32 + 255) / 256, b256, 0, stream>>>(
      z2b, z2b, st4, bn4_g, bn4_b, NP * 32, 128, 1.0f / NP);
  mfma_gemm<false, false><<<dim3(1, 2048), b256, 0, stream>>>(
      z2b, FWT, out, NP, 65, 128, 65, fb, nullptr);
}